// Round 1
// baseline (314.375 us; speedup 1.0000x reference)
//
#include <hip/hip_runtime.h>
#include <hip/hip_bf16.h>

#define V 12288
#define D 128
#define BB 256
#define LL 64
#define P_PAIRS 200000
#define CC 1500

typedef __bf16 bf16x8 __attribute__((ext_vector_type(8)));
typedef float floatx4 __attribute__((ext_vector_type(4)));

typedef __attribute__((address_space(1))) const void* as1_cvp;
typedef __attribute__((address_space(3))) void* as3_vp;

// ---------- init: convert embedding to bf16, zero norms & out ----------
__global__ void k_init(const float* __restrict__ emb, __bf16* __restrict__ e16,
                       float* __restrict__ norms, float* __restrict__ out) {
    int t = blockIdx.x * blockDim.x + threadIdx.x;
    if (t < V * D) e16[t] = (__bf16)emb[t];
    if (t < V) norms[t] = 0.0f;
    if (t == 0) out[0] = 0.0f;
}

// ---------- visit representation: masked sum over codes + tanh ----------
__global__ void k_visit_rep(const int* __restrict__ x, const float* __restrict__ emb,
                            float* __restrict__ vrep) {
    __shared__ int xs[LL];
    const int b = blockIdx.x;
    const int d = threadIdx.x;            // 128 threads
    if (threadIdx.x < LL) xs[threadIdx.x] = x[b * LL + threadIdx.x];
    __syncthreads();
    float s = 0.f;
    #pragma unroll 4
    for (int l = 0; l < LL; ++l) {
        int xi = xs[l];
        if (xi != 0) s += emb[xi * D + d];
    }
    vrep[b * D + d] = tanhf(s);
}

// ---------- visit cost: logits -> softmax -> CE, one block per visit ----------
__global__ __launch_bounds__(256)
void k_visit_cost(const float* __restrict__ vrep, const float* __restrict__ Wc,
                  const float* __restrict__ bc, const float* __restrict__ lab,
                  float* __restrict__ out) {
    __shared__ float vr[D];
    __shared__ float logits[CC];
    __shared__ float sred[4];
    const int b = blockIdx.x;
    const int t = threadIdx.x;            // 256 threads
    if (t < D) vr[t] = vrep[b * D + t];
    __syncthreads();

    float lmax = -3.4e38f;
    for (int c = t; c < CC; c += 256) {
        float dot = bc[c];
        #pragma unroll 8
        for (int d = 0; d < D; ++d) dot = fmaf(vr[d], Wc[d * CC + c], dot);
        logits[c] = dot;
        lmax = fmaxf(lmax, dot);
    }
    #pragma unroll
    for (int off = 32; off; off >>= 1) lmax = fmaxf(lmax, __shfl_xor(lmax, off));
    if ((t & 63) == 0) sred[t >> 6] = lmax;
    __syncthreads();
    float m = fmaxf(fmaxf(sred[0], sred[1]), fmaxf(sred[2], sred[3]));
    __syncthreads();

    float lsum = 0.f;
    for (int c = t; c < CC; c += 256) lsum += __expf(logits[c] - m);
    #pragma unroll
    for (int off = 32; off; off >>= 1) lsum += __shfl_xor(lsum, off);
    if ((t & 63) == 0) sred[t >> 6] = lsum;
    __syncthreads();
    float logZ = logf(sred[0] + sred[1] + sred[2] + sred[3]);
    __syncthreads();

    float acc = 0.f;
    for (int c = t; c < CC; c += 256) {
        float p = __expf(logits[c] - m - logZ);
        float la = lab[b * CC + c];
        acc += la * logf(p + 1e-5f) + (1.f - la) * logf(1.f - p + 1e-5f);
    }
    #pragma unroll
    for (int off = 32; off; off >>= 1) acc += __shfl_xor(acc, off);
    if ((t & 63) == 0) sred[t >> 6] = acc;
    __syncthreads();
    if (t == 0) {
        float s = sred[0] + sred[1] + sred[2] + sred[3];
        atomicAdd(out, -s * (1.0f / BB));
    }
}

// ---------- gram row sums: norms[i] = sum_j exp(e_i . e_j) ----------
// 128x128 tile per block, K=128 in one shot, bf16 MFMA 16x16x32.
// LDS staged via global_load_lds(width=16) with pre-swizzled global source:
// chunk c (16B units) holds global chunk c ^ ((c>>4)&7)  (involution).
__global__ __launch_bounds__(256, 2)
void k_gram(const __bf16* __restrict__ e16, float* __restrict__ norms) {
    __shared__ __bf16 ldsA[128 * 128];
    __shared__ __bf16 ldsB[128 * 128];
    const int bi = blockIdx.x;            // i-panel (rows)
    const int bj = blockIdx.y;            // j-panel (cols)
    const int tid  = threadIdx.x;
    const int wave = tid >> 6;
    const int lane = tid & 63;

    const __bf16* Apan = e16 + (size_t)bi * 128 * 128;   // rows contiguous: D=128
    const __bf16* Bpan = e16 + (size_t)bj * 128 * 128;

    #pragma unroll
    for (int it = 0; it < 8; ++it) {
        int c = (wave * 8 + it) * 64 + lane;   // lds chunk index 0..2047
        int g = c ^ ((c >> 4) & 7);            // swizzled global chunk
        __builtin_amdgcn_global_load_lds((as1_cvp)(Apan + g * 8),
                                         (as3_vp)(ldsA + c * 8), 16, 0, 0);
        __builtin_amdgcn_global_load_lds((as1_cvp)(Bpan + g * 8),
                                         (as3_vp)(ldsB + c * 8), 16, 0, 0);
    }
    __syncthreads();

    const int wr = wave >> 1, wc = wave & 1;   // 2x2 waves, 64x64 each
    const int l15 = lane & 15, l4 = lane >> 4;

    floatx4 acc[4][4];
    #pragma unroll
    for (int m = 0; m < 4; ++m)
        #pragma unroll
        for (int n = 0; n < 4; ++n) acc[m][n] = (floatx4){0.f, 0.f, 0.f, 0.f};

    #pragma unroll
    for (int ks = 0; ks < 4; ++ks) {           // K = 4 x 32
        const int kc = ks * 4 + l4;            // 16B chunk within row
        bf16x8 af[4], bf[4];
        #pragma unroll
        for (int m = 0; m < 4; ++m) {
            int row = wr * 64 + m * 16 + l15;
            int ch = (row * 16 + kc) ^ (row & 7);
            af[m] = *(const bf16x8*)&ldsA[ch * 8];
        }
        #pragma unroll
        for (int n = 0; n < 4; ++n) {
            int row = wc * 64 + n * 16 + l15;
            int ch = (row * 16 + kc) ^ (row & 7);
            bf[n] = *(const bf16x8*)&ldsB[ch * 8];
        }
        #pragma unroll
        for (int m = 0; m < 4; ++m)
            #pragma unroll
            for (int n = 0; n < 4; ++n)
                acc[m][n] = __builtin_amdgcn_mfma_f32_16x16x32_bf16(af[m], bf[n], acc[m][n], 0, 0, 0);
    }

    // epilogue: exp, row-sum across the 64 cols this wave owns, atomic into norms
    #pragma unroll
    for (int m = 0; m < 4; ++m) {
        float rs[4];
        #pragma unroll
        for (int r = 0; r < 4; ++r) {
            float v = 0.f;
            #pragma unroll
            for (int n = 0; n < 4; ++n) v += __expf(acc[m][n][r]);
            #pragma unroll
            for (int off = 1; off < 16; off <<= 1) v += __shfl_xor(v, off, 16);
            rs[r] = v;
        }
        if (l15 == 0) {
            int rowg = bi * 128 + wr * 64 + m * 16 + l4 * 4;
            #pragma unroll
            for (int r = 0; r < 4; ++r) atomicAdd(&norms[rowg + r], rs[r]);
        }
    }
}

// ---------- pair term: mean(-log(exp(ei.ej)/norms[i] + 1e-8)) ----------
__global__ __launch_bounds__(256)
void k_pairs(const int* __restrict__ iv, const int* __restrict__ jv,
             const __bf16* __restrict__ e16, const float* __restrict__ norms,
             float* __restrict__ out) {
    __shared__ float part[16];
    const int t = threadIdx.x;
    const int g = t >> 4;                 // 16 pairs per block
    const int l = t & 15;                 // 16 lanes per pair
    const int p = blockIdx.x * 16 + g;
    const int i = iv[p];
    const int j = jv[p];
    bf16x8 a = *(const bf16x8*)(e16 + (size_t)i * D + l * 8);
    bf16x8 bb = *(const bf16x8*)(e16 + (size_t)j * D + l * 8);
    float dot = 0.f;
    #pragma unroll
    for (int q = 0; q < 8; ++q) dot = fmaf((float)a[q], (float)bb[q], dot);
    #pragma unroll
    for (int off = 1; off < 16; off <<= 1) dot += __shfl_xor(dot, off, 16);
    if (l == 0) {
        float denom = __expf(dot);
        part[g] = -logf(denom / norms[i] + 1e-8f);
    }
    __syncthreads();
    if (t == 0) {
        float s = 0.f;
        #pragma unroll
        for (int q = 0; q < 16; ++q) s += part[q];
        atomicAdd(out, s * (1.0f / P_PAIRS));
    }
}

extern "C" void kernel_launch(void* const* d_in, const int* in_sizes, int n_in,
                              void* d_out, int out_size, void* d_ws, size_t ws_size,
                              hipStream_t stream) {
    const int*   x   = (const int*)  d_in[0];
    const int*   iv  = (const int*)  d_in[1];
    const int*   jv  = (const int*)  d_in[2];
    const float* lab = (const float*)d_in[3];
    const float* emb = (const float*)d_in[4];
    const float* Wc  = (const float*)d_in[5];
    const float* bc  = (const float*)d_in[6];
    float* out = (float*)d_out;

    char* ws = (char*)d_ws;
    __bf16* e16  = (__bf16*)ws;                          // V*D*2   = 3,145,728 B
    float* norms = (float*)(ws + 3145728);               // V*4     =    49,152 B
    float* vrep  = (float*)(ws + 3145728 + 49152);       // B*D*4   =   131,072 B

    k_init<<<(V * D + 255) / 256, 256, 0, stream>>>(emb, e16, norms, out);
    k_visit_rep<<<BB, D, 0, stream>>>(x, emb, vrep);
    k_visit_cost<<<BB, 256, 0, stream>>>(vrep, Wc, bc, lab, out);
    dim3 g3(V / 128, V / 128);
    k_gram<<<g3, 256, 0, stream>>>(e16, norms);
    k_pairs<<<P_PAIRS / 16, 256, 0, stream>>>(iv, jv, e16, norms, out);
}